// Round 1
// baseline (300.238 us; speedup 1.0000x reference)
//
#include <hip/hip_runtime.h>

// out[b,i,h,j] = x[b,0,h,j+i] * z[b,0,h,j], zero where j+i >= W.
// B=4, H=512, W=2048, WC=16. fp32 in/out.
// Floor: 268 MB write + 33.5 MB read => ~48 us at 6.3 TB/s.
//
// R3: one block per INPUT row (b,h) instead of per output row.
// Old layout re-read every x/z row 16x (once per shift i) => ~537 MB of
// LLC-level read traffic sharing the fabric with the 268 MB write stream
// (~805 MB @ ~6.5 TB/s ~= the observed ~123 us kernel time).
// Now: x row staged once in LDS (zero-padded tail => masking and the
// last-row OOB special case vanish: pad * z == +0.0 exactly), z kept in
// registers, and each block emits all 16 shifted output rows.
// Reads drop 16x; kernel becomes write-BW-bound.

#define B_ 4
#define H_ 512
#define W_ 2048
#define WC_ 16

__global__ __launch_bounds__(256) void
space2features_kernel(const float* __restrict__ x,
                      const float* __restrict__ z,
                      float* __restrict__ out) {
    // Row + zero tail: windows read up to xs[j + 19] (j <= 2044).
    __shared__ float xs[W_ + 20];

    const int blk = blockIdx.x;              // b*H + h
    const int h = blk & (H_ - 1);
    const int b = blk >> 9;

    const size_t inrow = (size_t)blk * W_;
    const float* __restrict__ xr = x + inrow;
    const float* __restrict__ zr = z + inrow;

    const int t = threadIdx.x;

    // Stage x row into LDS; keep z in registers (aligned with output j).
    float4 zv[2];
#pragma unroll
    for (int half = 0; half < 2; ++half) {
        const int j = half * 1024 + t * 4;   // 16B-aligned
        const float4 x4 = *(const float4*)(xr + j);
        zv[half] = *(const float4*)(zr + j);
        *(float4*)(xs + j) = x4;
    }
    if (t < 20) xs[W_ + t] = 0.0f;           // zero tail => implicit mask
    __syncthreads();

    // out[((b*WC + i)*H + h)*W + j] = obase + i*H*W + j
    float* __restrict__ obase = out + ((size_t)(b * WC_) * H_ + h) * W_;

#pragma unroll
    for (int half = 0; half < 2; ++half) {
        const int j = half * 1024 + t * 4;

        // 20-float aligned window: 5x conflict-free ds_read_b128.
        // All indices below are compile-time after unrolling -> registers,
        // and every shift i becomes pure register selects.
        float xv[20];
#pragma unroll
        for (int g = 0; g < 5; ++g)
            *(float4*)(xv + 4 * g) = *(const float4*)(xs + j + 4 * g);

        const float4 z4 = zv[half];
#pragma unroll
        for (int i = 0; i < WC_; ++i) {
            float4 o;
            o.x = xv[i + 0] * z4.x;
            o.y = xv[i + 1] * z4.y;
            o.z = xv[i + 2] * z4.z;
            o.w = xv[i + 3] * z4.w;
            *(float4*)(obase + (size_t)i * (H_ * W_) + j) = o;
        }
    }
}

extern "C" void kernel_launch(void* const* d_in, const int* in_sizes, int n_in,
                              void* d_out, int out_size, void* d_ws, size_t ws_size,
                              hipStream_t stream) {
    const float* x = (const float*)d_in[0];
    const float* z = (const float*)d_in[1];
    float* out = (float*)d_out;

    const int grid = B_ * H_;                // 2048 blocks, one per input row
    space2features_kernel<<<grid, 256, 0, stream>>>(x, z, out);
}